// Round 17
// baseline (155.520 us; speedup 1.0000x reference)
//
#include <hip/hip_runtime.h>
#include <stdint.h>

#define HNUM 240
#define WNUM 1216
#define BNUM 4
#define HWN (HNUM * WNUM)
#define NPIX (BNUM * HWN)
#define NP2T (NPIX / 2)           /* 583680 threads for meta build */
#define GRIDM (NP2T / 256)        /* 2280 blocks */

/* prop tile */
#define TR 16
#define TC 64
#define RH 8                      /* s4 displacement <= 8 -> halo 8 suffices */
#define LR (TR + 2 * RH + 1)      /* 33 */
#define LC (TC + 2 * RH + 1)      /* 81 */
#define LCP 82                    /* row stride (even -> dword-aligned rows) */
#define LDSN (LR * LCP)           /* 2706 */
#define LDSW (LDSN / 2)           /* 1353 dwords */
#define ROWW (LCP / 2)            /* 41 dwords per row */
#define PXJ 4
#define TGR (HNUM / TR)           /* 15 */
#define TGC (WNUM / TC)           /* 19 */
#define NTILE (BNUM * TGR * TGC)  /* 1140 */

union HCV { uint32_t u; _Float16 h[2]; };

__device__ __forceinline__ float fast_tanh(float x) {
    float ax = fabsf(x);
    float e  = __builtin_amdgcn_exp2f(ax * 2.885390081777927f);  // 2*log2(e)
    float t  = 1.0f - 2.0f * __builtin_amdgcn_rcpf(e + 1.0f);
    return copysignf(t, x);
}

// ---------------------------------------------------------------------------
// meta build (pure streaming): 2 px/thread, float2 loads, with a scheduler
// fence after the load phase so ALL 29 loads stay in flight (MLP forcing).
// tap u32 = drow s4 | dcol s4 | qy u8 <<8 | qx u8 <<16 | aff s8 <<24
// aux uint2 = { half2(aref, conf), dep f32 }.  Also writes ff0 = pred*conf.
// ---------------------------------------------------------------------------
__global__ __launch_bounds__(256, 6) void nlspn_meta_build(
    const float* __restrict__ aff_raw,
    const float* __restrict__ offset,
    const float* __restrict__ conf,
    const float* __restrict__ dep,
    const float* __restrict__ pred,
    const float* __restrict__ scale,
    _Float16* __restrict__ plane0,
    uint4* __restrict__ tapsA,
    uint4* __restrict__ tapsB,
    uint2* __restrict__ auxv)
{
    int t = blockIdx.x * 256 + (int)threadIdx.x;   // < NP2T exactly
    int p0 = 2 * t;
    int b  = p0 / HWN;
    int hw = p0 - b * HWN;
    int h  = hw / WNUM;
    int w0 = hw - h * WNUM;                        // even; pair same row

    float s    = scale[0];
    float invs = 1.0f / (s + 1e-8f);

    const float* arb = aff_raw + (size_t)b * 8 * HWN + hw;
    const float* ofb = offset  + (size_t)b * 16 * HWN + hw;

    // ---- load phase: issue everything, then fence the scheduler ----
    float2 ar2[8], oy2[8], ox2[8];
#pragma unroll
    for (int k = 0; k < 8; ++k)
        ar2[k] = *(const float2*)(arb + (size_t)k * HWN);
#pragma unroll
    for (int k = 0; k < 8; ++k) {
        oy2[k] = *(const float2*)(ofb + (size_t)(2 * k)     * HWN);
        ox2[k] = *(const float2*)(ofb + (size_t)(2 * k + 1) * HWN);
    }
    float2 cf2 = *(const float2*)(conf + p0);
    float2 dd2 = *(const float2*)(dep  + p0);
    float2 pp2 = *(const float2*)(pred + p0);

    __builtin_amdgcn_sched_barrier(0);   // loads may not sink past this point

    _Float16 plo[2];

#pragma unroll
    for (int jj = 0; jj < 2; ++jj) {
        int w = w0 + jj;
        float cf = (jj == 0) ? cf2.x : cf2.y;
        float dd = (jj == 0) ? dd2.x : dd2.y;
        float pp = (jj == 0) ? pp2.x : pp2.y;

        // affinity normalization
        float aa[8];
        float asum = 0.f;
#pragma unroll
        for (int k = 0; k < 8; ++k) {
            float rv = (jj == 0) ? ar2[k].x : ar2[k].y;
            float v  = fast_tanh(rv) * invs;
            aa[k] = v;
            asum += fabsf(v);
        }
        float rden = 1.0f / fmaxf(asum + 1e-4f, 1.0f);
        float sm = 0.f;
#pragma unroll
        for (int k = 0; k < 8; ++k) { aa[k] *= rden; sm += aa[k]; }
        float aref = 1.0f - sm;

        // taps (aff s8 embedded)
        uint32_t tw[8];
#pragma unroll
        for (int k = 0; k < 8; ++k) {
            int k9 = (k < 4) ? k : k + 1;
            int dy = k9 / 3 - 1;
            int dx = k9 - (k9 / 3) * 3 - 1;
            float offy = (jj == 0) ? oy2[k].x : oy2[k].y;
            float offx = (jj == 0) ? ox2[k].x : ox2[k].y;
            float ys  = (float)(h + dy) + offy;
            float xs  = (float)(w + dx) + offx;
            float y0f = floorf(ys), x0f = floorf(xs);
            float wyf = ys - y0f,   wxf = xs - x0f;
            int y0 = (int)y0f;
            int x0 = (int)x0f;
            int drow = y0 - h;
            int dcol = x0 - w;
            uint32_t qy = (uint32_t)(wyf * 255.0f + 0.5f); if (qy > 255) qy = 255;
            uint32_t qx = (uint32_t)(wxf * 255.0f + 0.5f); if (qx > 255) qx = 255;
            float av = aa[k];
            bool ok = (y0 >= -1) & (y0 <= HNUM) & (x0 >= -1) & (x0 <= WNUM)
                    & (drow >= -8) & (drow <= 7) & (dcol >= -8) & (dcol <= 7);
            if (!ok) { drow = 0; dcol = 0; qy = 0; qx = 0; av = 0.f; }
            int q8 = (int)floorf(av * 127.0f + 0.5f);
            q8 = (q8 < -127) ? -127 : ((q8 > 127) ? 127 : q8);
            tw[k] = ((uint32_t)drow & 0xfu)
                  | (((uint32_t)dcol & 0xfu) << 4)
                  | (qy << 8) | (qx << 16)
                  | ((uint32_t)(uint8_t)(int8_t)q8 << 24);
        }

        tapsA[p0 + jj] = make_uint4(tw[0], tw[1], tw[2], tw[3]);
        tapsB[p0 + jj] = make_uint4(tw[4], tw[5], tw[6], tw[7]);

        HCV cv;
        cv.h[0] = (_Float16)aref;
        cv.h[1] = (_Float16)cf;
        auxv[p0 + jj] = make_uint2(cv.u, __float_as_uint(dd));

        plo[jj] = (_Float16)(pp * cf);
    }

    HCV pv;
    pv.h[0] = plo[0];
    pv.h[1] = plo[1];
    *(uint32_t*)(plane0 + p0) = pv.u;
}

// ---------------------------------------------------------------------------
// propagation step: plane tile in LDS (halo 8), dword-vectorized staging,
// 33 LDS gathers/px, meta streamed
// ---------------------------------------------------------------------------
template <bool LAST>
__global__ __launch_bounds__(256) void nlspn_prop_lds(
    const uint4* __restrict__ tapsA,
    const uint4* __restrict__ tapsB,
    const uint2* __restrict__ auxv,
    const _Float16* __restrict__ planeIn,
    _Float16* __restrict__ planeOut,
    float* __restrict__ out)
{
    __shared__ _Float16 tile[LDSN];

    int bid  = blockIdx.x;
    int b    = bid / (TGR * TGC);
    int rem  = bid - b * (TGR * TGC);
    int tr   = rem / TGC;
    int tc   = rem - tr * TGC;
    int tid  = (int)threadIdx.x;
    int lane = tid & 63;
    int wrow = tid >> 6;

    int row0 = tr * TR - RH;
    int col0 = tc * TC - RH;       // always even
    const _Float16* pb = planeIn + (size_t)b * HWN;

    // ---- stage: dword pairs (rows dword-aligned, col0 even) ----
    for (int di = tid; di < LDSW; di += 256) {
        int lr  = di / ROWW;
        int lc2 = (di - lr * ROWW) * 2;     // even local col
        int gr  = row0 + lr;
        int gc  = col0 + lc2;               // even global col
        uint32_t v = 0u;
        if (gr >= 0 && gr < HNUM) {
            if (gc >= 0 && gc + 1 < WNUM && lc2 + 1 < LC) {
                v = *(const uint32_t*)(pb + gr * WNUM + gc);
            } else {
                HCV cv;
                cv.h[0] = (lc2 < LC && gc >= 0 && gc < WNUM)
                        ? pb[gr * WNUM + gc] : (_Float16)0.f;
                cv.h[1] = (lc2 + 1 < LC && gc + 1 >= 0 && gc + 1 < WNUM)
                        ? pb[gr * WNUM + gc + 1] : (_Float16)0.f;
                v = cv.u;
            }
        }
        *(uint32_t*)&tile[lr * LCP + lc2] = v;
    }
    __syncthreads();

#pragma unroll
    for (int j = 0; j < PXJ; ++j) {
        int rj = wrow * PXJ + j;
        int h  = tr * TR + rj;
        int w  = tc * TC + lane;
        int p  = b * HWN + h * WNUM + w;

        uint4 tA = tapsA[p];
        uint4 tB = tapsB[p];
        uint2 ax = auxv[p];

        HCV cv; cv.u = ax.x;
        float aref = (float)cv.h[0];
        float cf   = (float)cv.h[1];
        float dd   = __uint_as_float(ax.y);

        int cbase = (RH + rj) * LCP + (RH + lane);
        float acc = aref * (float)tile[cbase];

        uint32_t tm[8] = {tA.x, tA.y, tA.z, tA.w, tB.x, tB.y, tB.z, tB.w};
#pragma unroll
        for (int k = 0; k < 8; ++k) {
            uint32_t m = tm[k];
            int drow = ((int)(m << 28)) >> 28;
            int dcol = ((int)(m << 24)) >> 28;
            float wy = (float)((m >> 8)  & 0xffu) * (1.0f / 255.0f);
            float wx = (float)((m >> 16) & 0xffu) * (1.0f / 255.0f);
            float af = (float)((int)m >> 24) * (1.0f / 127.0f);
            int la = cbase + drow * LCP + dcol;
            float g00 = (float)tile[la];
            float g01 = (float)tile[la + 1];
            float g10 = (float)tile[la + LCP];
            float g11 = (float)tile[la + LCP + 1];
            float top = fmaf(wx, g01 - g00, g00);
            float bot = fmaf(wx, g11 - g10, g10);
            acc = fmaf(af, fmaf(wy, bot - top, top), acc);
        }

        float feat = (dd > 0.f) ? dd : acc;
        if (LAST) out[p] = feat;
        else      planeOut[p] = (_Float16)(feat * cf);
    }
}

// ---------------------------------------------------------------------------
// fallback (round-1 style) if workspace is too small
// ---------------------------------------------------------------------------
__global__ __launch_bounds__(256) void nlspn_init_kernel(
    const float* __restrict__ pred,
    const float* __restrict__ conf,
    float* __restrict__ ff)
{
    int p = blockIdx.x * blockDim.x + threadIdx.x;
    if (p < NPIX) ff[p] = pred[p] * conf[p];
}

template <bool LAST>
__global__ __launch_bounds__(256) void nlspn_prop_kernel(
    const float* __restrict__ aff_raw,
    const float* __restrict__ offset,
    const float* __restrict__ conf,
    const float* __restrict__ dep,
    const float* __restrict__ scale,
    const float* __restrict__ ff_in,
    float* __restrict__ out)
{
    int p = blockIdx.x * blockDim.x + threadIdx.x;
    if (p >= NPIX) return;
    int b  = p / HWN;
    int hw = p - b * HWN;
    int h  = hw / WNUM;
    int w  = hw - h * WNUM;

    float s    = scale[0];
    float invs = 1.0f / (s + 1e-8f);

    float a[8];
    const float* ar = aff_raw + (size_t)b * 8 * HWN + hw;
#pragma unroll
    for (int k = 0; k < 8; ++k) a[k] = ar[(size_t)k * HWN];

    float asum = 0.0f;
#pragma unroll
    for (int k = 0; k < 8; ++k) {
        a[k] = fast_tanh(a[k]) * invs;
        asum += fabsf(a[k]);
    }
    asum += 1e-4f;
    float rden = 1.0f / fmaxf(asum, 1.0f);
    float suma = 0.0f;
#pragma unroll
    for (int k = 0; k < 8; ++k) { a[k] *= rden; suma += a[k]; }
    float aref = 1.0f - suma;

    const float* ffb = ff_in + (size_t)b * HWN;
    float acc = aref * ffb[hw];

    const float* off = offset + (size_t)b * 16 * HWN + hw;
#pragma unroll
    for (int k = 0; k < 8; ++k) {
        int   k9 = (k < 4) ? k : k + 1;
        int   dy = k9 / 3 - 1;
        int   dx = k9 - (k9 / 3) * 3 - 1;
        float offy = off[(size_t)(2 * k)     * HWN];
        float offx = off[(size_t)(2 * k + 1) * HWN];
        float ysf = (float)(h + dy) + offy;
        float xsf = (float)(w + dx) + offx;
        float y0f = floorf(ysf);
        float x0f = floorf(xsf);
        float wy  = ysf - y0f;
        float wx  = xsf - x0f;
        int   y0  = (int)y0f;
        int   x0  = (int)x0f;
        bool yv0 = (y0 >= 0)  & (y0 < HNUM);
        bool yv1 = (y0 >= -1) & (y0 + 1 < HNUM);
        bool xv0 = (x0 >= 0)  & (x0 < WNUM);
        bool xv1 = (x0 >= -1) & (x0 + 1 < WNUM);
        int row0 = y0 * WNUM;
        float g00 = 0.f, g01 = 0.f, g10 = 0.f, g11 = 0.f;
        if (yv0 & xv0) g00 = ffb[row0 + x0];
        if (yv0 & xv1) g01 = ffb[row0 + x0 + 1];
        if (yv1 & xv0) g10 = ffb[row0 + WNUM + x0];
        if (yv1 & xv1) g11 = ffb[row0 + WNUM + x0 + 1];
        float sampled = (1.f - wy) * ((1.f - wx) * g00 + wx * g01)
                      +        wy  * ((1.f - wx) * g10 + wx * g11);
        acc += a[k] * sampled;
    }

    float dd   = dep[p];
    float feat = (dd > 0.0f) ? dd : acc;
    if (LAST) out[p] = feat;
    else      out[p] = feat * conf[p];
}

// ---------------------------------------------------------------------------
extern "C" void kernel_launch(void* const* d_in, const int* in_sizes, int n_in,
                              void* d_out, int out_size, void* d_ws, size_t ws_size,
                              hipStream_t stream)
{
    const float* aff_raw = (const float*)d_in[0];
    const float* offset  = (const float*)d_in[1];
    const float* conf    = (const float*)d_in[2];
    const float* pred    = (const float*)d_in[3];
    const float* dep     = (const float*)d_in[4];
    const float* scale   = (const float*)d_in[5];
    float* out = (float*)d_out;

    const int threads = 256;
    const size_t need = (size_t)NPIX * 44 + 64;

    if (ws_size >= need) {
        char* wb = (char*)d_ws;
        uint4* tapsA  = (uint4*)wb;  wb += (size_t)NPIX * 16;
        uint4* tapsB  = (uint4*)wb;  wb += (size_t)NPIX * 16;
        uint2* auxv   = (uint2*)wb;  wb += (size_t)NPIX * 8;
        _Float16* plA = (_Float16*)wb;  wb += (size_t)NPIX * 2;
        _Float16* plB = (_Float16*)wb;

        nlspn_meta_build<<<GRIDM, threads, 0, stream>>>(
            aff_raw, offset, conf, dep, pred, scale,
            plA, tapsA, tapsB, auxv);                                       // ff0 -> A
        nlspn_prop_lds<false><<<NTILE, threads, 0, stream>>>(
            tapsA, tapsB, auxv, plA, plB, out);                             // ff1 -> B
        nlspn_prop_lds<false><<<NTILE, threads, 0, stream>>>(
            tapsA, tapsB, auxv, plB, plA, out);                             // ff2 -> A
        nlspn_prop_lds<false><<<NTILE, threads, 0, stream>>>(
            tapsA, tapsB, auxv, plA, plB, out);                             // ff3 -> B
        nlspn_prop_lds<false><<<NTILE, threads, 0, stream>>>(
            tapsA, tapsB, auxv, plB, plA, out);                             // ff4 -> A
        nlspn_prop_lds<false><<<NTILE, threads, 0, stream>>>(
            tapsA, tapsB, auxv, plA, plB, out);                             // ff5 -> B
        nlspn_prop_lds<true><<<NTILE, threads, 0, stream>>>(
            tapsA, tapsB, auxv, plB, plA, out);                             // feat6 -> d_out
    } else {
        const int blocksP = (NPIX + threads - 1) / threads;
        float* ws = (float*)d_ws;
        nlspn_init_kernel<<<blocksP, threads, 0, stream>>>(pred, conf, out);
        nlspn_prop_kernel<false><<<blocksP, threads, 0, stream>>>(aff_raw, offset, conf, dep, scale, out, ws);
        nlspn_prop_kernel<false><<<blocksP, threads, 0, stream>>>(aff_raw, offset, conf, dep, scale, ws, out);
        nlspn_prop_kernel<false><<<blocksP, threads, 0, stream>>>(aff_raw, offset, conf, dep, scale, out, ws);
        nlspn_prop_kernel<false><<<blocksP, threads, 0, stream>>>(aff_raw, offset, conf, dep, scale, ws, out);
        nlspn_prop_kernel<false><<<blocksP, threads, 0, stream>>>(aff_raw, offset, conf, dep, scale, out, ws);
        nlspn_prop_kernel<true ><<<blocksP, threads, 0, stream>>>(aff_raw, offset, conf, dep, scale, ws, out);
    }
}

// Round 18
// 112.622 us; speedup vs baseline: 1.3809x; 1.3809x over previous
//
#include <hip/hip_runtime.h>
#include <stdint.h>

#define HNUM 240
#define WNUM 1216
#define BNUM 4
#define HWN (HNUM * WNUM)
#define NPIX (BNUM * HWN)
#define NP2T (NPIX / 2)           /* 583680 threads for meta build */
#define GRIDM (NP2T / 256)        /* 2280 blocks */

/* prop tile */
#define TR 16
#define TC 64
#define RH 8                      /* s4 displacement <= 8 -> halo 8 suffices */
#define LR (TR + 2 * RH + 1)      /* 33 */
#define LC (TC + 2 * RH + 1)      /* 81 */
#define LCP 82                    /* row stride */
#define LDSN (LR * LCP)           /* 2706 */
#define PXJ 4
#define TGR (HNUM / TR)           /* 15 */
#define TGC (WNUM / TC)           /* 19 */
#define NTILE (BNUM * TGR * TGC)  /* 1140 */

union HCV { uint32_t u; _Float16 h[2]; };

__device__ __forceinline__ float fast_tanh(float x) {
    float ax = fabsf(x);
    float e  = __builtin_amdgcn_exp2f(ax * 2.885390081777927f);  // 2*log2(e)
    float t  = 1.0f - 2.0f * __builtin_amdgcn_rcpf(e + 1.0f);
    return copysignf(t, x);
}

// ---------------------------------------------------------------------------
// meta build (pure streaming, no LDS): 2 px/thread, float2 loads.  [R13 exact]
// tap u32 = drow s4 | dcol s4 | qy u8 <<8 | qx u8 <<16 | aff s8 <<24
// aux uint2 = { half2(aref, conf), dep f32 }.  Also writes ff0 = pred*conf.
// ---------------------------------------------------------------------------
__global__ __launch_bounds__(256) void nlspn_meta_build(
    const float* __restrict__ aff_raw,
    const float* __restrict__ offset,
    const float* __restrict__ conf,
    const float* __restrict__ dep,
    const float* __restrict__ pred,
    const float* __restrict__ scale,
    _Float16* __restrict__ plane0,
    uint4* __restrict__ tapsA,
    uint4* __restrict__ tapsB,
    uint2* __restrict__ auxv)
{
    int t = blockIdx.x * 256 + (int)threadIdx.x;   // < NP2T exactly
    int p0 = 2 * t;
    int b  = p0 / HWN;
    int hw = p0 - b * HWN;
    int h  = hw / WNUM;
    int w0 = hw - h * WNUM;                        // even; pair same row

    float s    = scale[0];
    float invs = 1.0f / (s + 1e-8f);

    const float* arb = aff_raw + (size_t)b * 8 * HWN + hw;
    const float* ofb = offset  + (size_t)b * 16 * HWN + hw;

    float2 ar2[8], oy2[8], ox2[8];
#pragma unroll
    for (int k = 0; k < 8; ++k)
        ar2[k] = *(const float2*)(arb + (size_t)k * HWN);
#pragma unroll
    for (int k = 0; k < 8; ++k) {
        oy2[k] = *(const float2*)(ofb + (size_t)(2 * k)     * HWN);
        ox2[k] = *(const float2*)(ofb + (size_t)(2 * k + 1) * HWN);
    }
    float2 cf2 = *(const float2*)(conf + p0);
    float2 dd2 = *(const float2*)(dep  + p0);
    float2 pp2 = *(const float2*)(pred + p0);

    _Float16 plo[2];

#pragma unroll
    for (int jj = 0; jj < 2; ++jj) {
        int w = w0 + jj;
        float cf = (jj == 0) ? cf2.x : cf2.y;
        float dd = (jj == 0) ? dd2.x : dd2.y;
        float pp = (jj == 0) ? pp2.x : pp2.y;

        // affinity normalization
        float aa[8];
        float asum = 0.f;
#pragma unroll
        for (int k = 0; k < 8; ++k) {
            float rv = (jj == 0) ? ar2[k].x : ar2[k].y;
            float v  = fast_tanh(rv) * invs;
            aa[k] = v;
            asum += fabsf(v);
        }
        float rden = 1.0f / fmaxf(asum + 1e-4f, 1.0f);
        float sm = 0.f;
#pragma unroll
        for (int k = 0; k < 8; ++k) { aa[k] *= rden; sm += aa[k]; }
        float aref = 1.0f - sm;

        // taps (aff s8 embedded)
        uint32_t tw[8];
#pragma unroll
        for (int k = 0; k < 8; ++k) {
            int k9 = (k < 4) ? k : k + 1;
            int dy = k9 / 3 - 1;
            int dx = k9 - (k9 / 3) * 3 - 1;
            float offy = (jj == 0) ? oy2[k].x : oy2[k].y;
            float offx = (jj == 0) ? ox2[k].x : ox2[k].y;
            float ys  = (float)(h + dy) + offy;
            float xs  = (float)(w + dx) + offx;
            float y0f = floorf(ys), x0f = floorf(xs);
            float wyf = ys - y0f,   wxf = xs - x0f;
            int y0 = (int)y0f;
            int x0 = (int)x0f;
            int drow = y0 - h;
            int dcol = x0 - w;
            uint32_t qy = (uint32_t)(wyf * 255.0f + 0.5f); if (qy > 255) qy = 255;
            uint32_t qx = (uint32_t)(wxf * 255.0f + 0.5f); if (qx > 255) qx = 255;
            float av = aa[k];
            bool ok = (y0 >= -1) & (y0 <= HNUM) & (x0 >= -1) & (x0 <= WNUM)
                    & (drow >= -8) & (drow <= 7) & (dcol >= -8) & (dcol <= 7);
            if (!ok) { drow = 0; dcol = 0; qy = 0; qx = 0; av = 0.f; }
            int q8 = (int)floorf(av * 127.0f + 0.5f);
            q8 = (q8 < -127) ? -127 : ((q8 > 127) ? 127 : q8);
            tw[k] = ((uint32_t)drow & 0xfu)
                  | (((uint32_t)dcol & 0xfu) << 4)
                  | (qy << 8) | (qx << 16)
                  | ((uint32_t)(uint8_t)(int8_t)q8 << 24);
        }

        tapsA[p0 + jj] = make_uint4(tw[0], tw[1], tw[2], tw[3]);
        tapsB[p0 + jj] = make_uint4(tw[4], tw[5], tw[6], tw[7]);

        HCV cv;
        cv.h[0] = (_Float16)aref;
        cv.h[1] = (_Float16)cf;
        auxv[p0 + jj] = make_uint2(cv.u, __float_as_uint(dd));

        plo[jj] = (_Float16)(pp * cf);
    }

    HCV pv;
    pv.h[0] = plo[0];
    pv.h[1] = plo[1];
    *(uint32_t*)(plane0 + p0) = pv.u;
}

// ---------------------------------------------------------------------------
// propagation step: plane tile in LDS (halo 8), 33 LDS gathers/px, meta streamed
// ---------------------------------------------------------------------------
template <bool LAST>
__global__ __launch_bounds__(256) void nlspn_prop_lds(
    const uint4* __restrict__ tapsA,
    const uint4* __restrict__ tapsB,
    const uint2* __restrict__ auxv,
    const _Float16* __restrict__ planeIn,
    _Float16* __restrict__ planeOut,
    float* __restrict__ out)
{
    __shared__ _Float16 tile[LDSN];

    int bid  = blockIdx.x;
    int b    = bid / (TGR * TGC);
    int rem  = bid - b * (TGR * TGC);
    int tr   = rem / TGC;
    int tc   = rem - tr * TGC;
    int tid  = (int)threadIdx.x;
    int lane = tid & 63;
    int wrow = tid >> 6;

    int row0 = tr * TR - RH;
    int col0 = tc * TC - RH;
    const _Float16* pb = planeIn + (size_t)b * HWN;

    for (int i = tid; i < LDSN; i += 256) {
        int lr = i / LCP;
        int lc = i - lr * LCP;
        int gr = row0 + lr;
        int gc = col0 + lc;
        _Float16 v = (_Float16)0.f;
        if (lc < LC && gr >= 0 && gr < HNUM && gc >= 0 && gc < WNUM)
            v = pb[gr * WNUM + gc];
        tile[i] = v;
    }
    __syncthreads();

#pragma unroll
    for (int j = 0; j < PXJ; ++j) {
        int rj = wrow * PXJ + j;
        int h  = tr * TR + rj;
        int w  = tc * TC + lane;
        int p  = b * HWN + h * WNUM + w;

        uint4 tA = tapsA[p];
        uint4 tB = tapsB[p];
        uint2 ax = auxv[p];

        HCV cv; cv.u = ax.x;
        float aref = (float)cv.h[0];
        float cf   = (float)cv.h[1];
        float dd   = __uint_as_float(ax.y);

        int cbase = (RH + rj) * LCP + (RH + lane);
        float acc = aref * (float)tile[cbase];

        uint32_t tm[8] = {tA.x, tA.y, tA.z, tA.w, tB.x, tB.y, tB.z, tB.w};
#pragma unroll
        for (int k = 0; k < 8; ++k) {
            uint32_t m = tm[k];
            int drow = ((int)(m << 28)) >> 28;
            int dcol = ((int)(m << 24)) >> 28;
            float wy = (float)((m >> 8)  & 0xffu) * (1.0f / 255.0f);
            float wx = (float)((m >> 16) & 0xffu) * (1.0f / 255.0f);
            float af = (float)((int)m >> 24) * (1.0f / 127.0f);
            int la = cbase + drow * LCP + dcol;
            float g00 = (float)tile[la];
            float g01 = (float)tile[la + 1];
            float g10 = (float)tile[la + LCP];
            float g11 = (float)tile[la + LCP + 1];
            float top = fmaf(wx, g01 - g00, g00);
            float bot = fmaf(wx, g11 - g10, g10);
            acc = fmaf(af, fmaf(wy, bot - top, top), acc);
        }

        float feat = (dd > 0.f) ? dd : acc;
        if (LAST) out[p] = feat;
        else      planeOut[p] = (_Float16)(feat * cf);
    }
}

// ---------------------------------------------------------------------------
// fallback (round-1 style) if workspace is too small
// ---------------------------------------------------------------------------
__global__ __launch_bounds__(256) void nlspn_init_kernel(
    const float* __restrict__ pred,
    const float* __restrict__ conf,
    float* __restrict__ ff)
{
    int p = blockIdx.x * blockDim.x + threadIdx.x;
    if (p < NPIX) ff[p] = pred[p] * conf[p];
}

template <bool LAST>
__global__ __launch_bounds__(256) void nlspn_prop_kernel(
    const float* __restrict__ aff_raw,
    const float* __restrict__ offset,
    const float* __restrict__ conf,
    const float* __restrict__ dep,
    const float* __restrict__ scale,
    const float* __restrict__ ff_in,
    float* __restrict__ out)
{
    int p = blockIdx.x * blockDim.x + threadIdx.x;
    if (p >= NPIX) return;
    int b  = p / HWN;
    int hw = p - b * HWN;
    int h  = hw / WNUM;
    int w  = hw - h * WNUM;

    float s    = scale[0];
    float invs = 1.0f / (s + 1e-8f);

    float a[8];
    const float* ar = aff_raw + (size_t)b * 8 * HWN + hw;
#pragma unroll
    for (int k = 0; k < 8; ++k) a[k] = ar[(size_t)k * HWN];

    float asum = 0.0f;
#pragma unroll
    for (int k = 0; k < 8; ++k) {
        a[k] = fast_tanh(a[k]) * invs;
        asum += fabsf(a[k]);
    }
    asum += 1e-4f;
    float rden = 1.0f / fmaxf(asum, 1.0f);
    float suma = 0.0f;
#pragma unroll
    for (int k = 0; k < 8; ++k) { a[k] *= rden; suma += a[k]; }
    float aref = 1.0f - suma;

    const float* ffb = ff_in + (size_t)b * HWN;
    float acc = aref * ffb[hw];

    const float* off = offset + (size_t)b * 16 * HWN + hw;
#pragma unroll
    for (int k = 0; k < 8; ++k) {
        int   k9 = (k < 4) ? k : k + 1;
        int   dy = k9 / 3 - 1;
        int   dx = k9 - (k9 / 3) * 3 - 1;
        float offy = off[(size_t)(2 * k)     * HWN];
        float offx = off[(size_t)(2 * k + 1) * HWN];
        float ysf = (float)(h + dy) + offy;
        float xsf = (float)(w + dx) + offx;
        float y0f = floorf(ysf);
        float x0f = floorf(xsf);
        float wy  = ysf - y0f;
        float wx  = xsf - x0f;
        int   y0  = (int)y0f;
        int   x0  = (int)x0f;
        bool yv0 = (y0 >= 0)  & (y0 < HNUM);
        bool yv1 = (y0 >= -1) & (y0 + 1 < HNUM);
        bool xv0 = (x0 >= 0)  & (x0 < WNUM);
        bool xv1 = (x0 >= -1) & (x0 + 1 < WNUM);
        int row0 = y0 * WNUM;
        float g00 = 0.f, g01 = 0.f, g10 = 0.f, g11 = 0.f;
        if (yv0 & xv0) g00 = ffb[row0 + x0];
        if (yv0 & xv1) g01 = ffb[row0 + x0 + 1];
        if (yv1 & xv0) g10 = ffb[row0 + WNUM + x0];
        if (yv1 & xv1) g11 = ffb[row0 + WNUM + x0 + 1];
        float sampled = (1.f - wy) * ((1.f - wx) * g00 + wx * g01)
                      +        wy  * ((1.f - wx) * g10 + wx * g11);
        acc += a[k] * sampled;
    }

    float dd   = dep[p];
    float feat = (dd > 0.0f) ? dd : acc;
    if (LAST) out[p] = feat;
    else      out[p] = feat * conf[p];
}

// ---------------------------------------------------------------------------
extern "C" void kernel_launch(void* const* d_in, const int* in_sizes, int n_in,
                              void* d_out, int out_size, void* d_ws, size_t ws_size,
                              hipStream_t stream)
{
    const float* aff_raw = (const float*)d_in[0];
    const float* offset  = (const float*)d_in[1];
    const float* conf    = (const float*)d_in[2];
    const float* pred    = (const float*)d_in[3];
    const float* dep     = (const float*)d_in[4];
    const float* scale   = (const float*)d_in[5];
    float* out = (float*)d_out;

    const int threads = 256;
    const size_t need = (size_t)NPIX * 44 + 64;

    if (ws_size >= need) {
        char* wb = (char*)d_ws;
        uint4* tapsA  = (uint4*)wb;  wb += (size_t)NPIX * 16;
        uint4* tapsB  = (uint4*)wb;  wb += (size_t)NPIX * 16;
        uint2* auxv   = (uint2*)wb;  wb += (size_t)NPIX * 8;
        _Float16* plA = (_Float16*)wb;  wb += (size_t)NPIX * 2;
        _Float16* plB = (_Float16*)wb;

        nlspn_meta_build<<<GRIDM, threads, 0, stream>>>(
            aff_raw, offset, conf, dep, pred, scale,
            plA, tapsA, tapsB, auxv);                                       // ff0 -> A
        nlspn_prop_lds<false><<<NTILE, threads, 0, stream>>>(
            tapsA, tapsB, auxv, plA, plB, out);                             // ff1 -> B
        nlspn_prop_lds<false><<<NTILE, threads, 0, stream>>>(
            tapsA, tapsB, auxv, plB, plA, out);                             // ff2 -> A
        nlspn_prop_lds<false><<<NTILE, threads, 0, stream>>>(
            tapsA, tapsB, auxv, plA, plB, out);                             // ff3 -> B
        nlspn_prop_lds<false><<<NTILE, threads, 0, stream>>>(
            tapsA, tapsB, auxv, plB, plA, out);                             // ff4 -> A
        nlspn_prop_lds<false><<<NTILE, threads, 0, stream>>>(
            tapsA, tapsB, auxv, plA, plB, out);                             // ff5 -> B
        nlspn_prop_lds<true><<<NTILE, threads, 0, stream>>>(
            tapsA, tapsB, auxv, plB, plA, out);                             // feat6 -> d_out
    } else {
        const int blocksP = (NPIX + threads - 1) / threads;
        float* ws = (float*)d_ws;
        nlspn_init_kernel<<<blocksP, threads, 0, stream>>>(pred, conf, out);
        nlspn_prop_kernel<false><<<blocksP, threads, 0, stream>>>(aff_raw, offset, conf, dep, scale, out, ws);
        nlspn_prop_kernel<false><<<blocksP, threads, 0, stream>>>(aff_raw, offset, conf, dep, scale, ws, out);
        nlspn_prop_kernel<false><<<blocksP, threads, 0, stream>>>(aff_raw, offset, conf, dep, scale, out, ws);
        nlspn_prop_kernel<false><<<blocksP, threads, 0, stream>>>(aff_raw, offset, conf, dep, scale, ws, out);
        nlspn_prop_kernel<false><<<blocksP, threads, 0, stream>>>(aff_raw, offset, conf, dep, scale, out, ws);
        nlspn_prop_kernel<true ><<<blocksP, threads, 0, stream>>>(aff_raw, offset, conf, dep, scale, ws, out);
    }
}